// Round 1
// 72.550 us; speedup vs baseline: 1.0566x; 1.0566x over previous
//
#include <hip/hip_runtime.h>

// Problem constants: v (targets y), v_pred (queries x) are [4, 8192, 3] fp32.
#define BB 4
#define NN 8192
#define MM 8192
#define BN (BB * NN)

#define BLK 256        // threads per block = 4 waves
#define QB  256        // queries per block  = 8 A-tiles of 32 (2 per wave)
#define TC  1024       // targets per chunk  = 32 B-tiles of 32 (32 KB LDS image)
#define SCH (MM / TC)  // 8 y-chunks
#define NJT (TC / 32)  // 32 j-tiles per chunk
// grid (NN/QB, SCH, BB) = (32, 8, 4) = 1024 blocks = 4 blocks/CU (LDS 128KB/CU).

// Key encoding: key = KEY_C - d2, accumulated DIRECTLY by the MFMA (C = KEY_C,
// A/B packed so A.B = 2x.y - xx - yy). d2 <= (|x|+|y|)^2 ~ 100 < 128 for
// N(0,1) data, so keys are always positive floats; int-punned ordering == float
// ordering, and atomicMax(int) selects the smallest d2. The harness 0xAA ws
// poison (negative int) loses to any real key.
#define KEY_C 128.0f

typedef __bf16 bf16x8 __attribute__((ext_vector_type(8)));
typedef float  f32x16 __attribute__((ext_vector_type(16)));

// v_mfma_f32_32x32x16_bf16 layouts (guide §3, m74/m101 verified):
//   A: row = lane&31, k = (lane>>5)*8 + e   (8 bf16 per lane)
//   B: col = lane&31, k = (lane>>5)*8 + e
//   D: col = lane&31, row = (r&3) + 8*(r>>2) + 4*(lane>>5), r in [0,16)
//
// K-slot packing (K=16, fully used -> no wasted zero groups):
//   k0..3 : A {2x0h,2x0h,2x0l,2x0l}  B {y0h,y0l,y0h,y0l}   = 2*x0*y0 (exact)
//   k4..7 : same for dim 1
//   k8..11: same for dim 2
//   k12,13: A {-xx_h,-xx_l}          B {1,1}               = -xx
//   k14,15: A {1,1}                  B {-yy_h,-yy_l}       = -yy
// => D = KEY_C + 2x.y - xx - yy = KEY_C - d2 = key. Only error: bf16 rounding
// of the lo halves (~2^-17 rel ~ 1e-4 abs worst-case, sign-symmetric).

static __device__ inline void split_bf(float v, __bf16& h, __bf16& l) {
    h = (__bf16)v;
    l = (__bf16)(v - (float)h);
}

__global__ __launch_bounds__(BLK, 4) void chamfer_mfma(
    const float* __restrict__ y,    // v      [B, M, 3] targets
    const float* __restrict__ x,    // v_pred [B, N, 3] queries
    int* __restrict__ gkey)         // [B*N] int-punned keys (ws, poisoned)
{
    __shared__ uint4 FR[NJT * 64];  // 32 KB; holds A image (8 KB) then B image

    const int t  = threadIdx.x;
    const int l  = t & 63;
    const int w  = t >> 6;
    const int ib = blockIdx.x;   // query chunk
    const int s  = blockIdx.y;   // target chunk
    const int b  = blockIdx.z;   // batch

    // ---- stage A fragment image: 256 queries, 1 per thread ----
    {
        const float* xb = x + ((size_t)b * NN + (size_t)ib * QB) * 3;
        float x0 = xb[3*t+0], x1 = xb[3*t+1], x2 = xb[3*t+2];
        __bf16 h0,l0,h1,l1,h2,l2;
        split_bf(2.0f*x0, h0, l0);
        split_bf(2.0f*x1, h1, l1);
        split_bf(2.0f*x2, h2, l2);
        float nxx = -__builtin_fmaf(x2, x2, __builtin_fmaf(x1, x1, x0*x0));
        __bf16 hx, lx; split_bf(nxx, hx, lx);
        const __bf16 one = (__bf16)1.0f;
        bf16x8 g0 = {h0,h0,l0,l0,h1,h1,l1,l1};
        bf16x8 g1 = {h2,h2,l2,l2,hx,lx,one,one};
        const int at = t >> 5, col = t & 31;
        FR[at*64 +      col] = __builtin_bit_cast(uint4, g0);
        FR[at*64 + 32 + col] = __builtin_bit_cast(uint4, g1);
    }
    __syncthreads();
    const uint4 afr0 = FR[(w*2 + 0)*64 + l];
    const uint4 afr1 = FR[(w*2 + 1)*64 + l];
    __syncthreads();

    // ---- stage B fragment image: 1024 targets, 4 per thread (strided) ----
    {
        const float* yb = y + ((size_t)b * MM + (size_t)s * TC) * 3;
        const __bf16 one = (__bf16)1.0f;
#pragma unroll
        for (int k2 = 0; k2 < 4; ++k2) {
            const int j = t + k2 * BLK;
            float y0 = yb[3*j+0], y1 = yb[3*j+1], y2 = yb[3*j+2];
            __bf16 h0,l0,h1,l1,h2,l2;
            split_bf(y0, h0, l0);
            split_bf(y1, h1, l1);
            split_bf(y2, h2, l2);
            float nyy = -__builtin_fmaf(y2, y2, __builtin_fmaf(y1, y1, y0*y0));
            __bf16 hy, ly; split_bf(nyy, hy, ly);
            bf16x8 g0 = {h0,l0,h0,l0,h1,l1,h1,l1};
            bf16x8 g1 = {h2,l2,h2,l2,one,one,hy,ly};
            const int jt = j >> 5, col = j & 31;
            FR[jt*64 +      col] = __builtin_bit_cast(uint4, g0);
            FR[jt*64 + 32 + col] = __builtin_bit_cast(uint4, g1);
        }
    }
    __syncthreads();

    // ---- main loop: 32 j-tiles x 2 i-tiles of MFMA, v_max fold ----
    f32x16 ck;
#pragma unroll
    for (int r = 0; r < 16; ++r) ck[r] = KEY_C;
    f32x16 best0, best1;
#pragma unroll
    for (int r = 0; r < 16; ++r) { best0[r] = -3.4e38f; best1[r] = -3.4e38f; }

    const bf16x8 a0 = __builtin_bit_cast(bf16x8, afr0);
    const bf16x8 a1 = __builtin_bit_cast(bf16x8, afr1);

#pragma unroll 2
    for (int jt = 0; jt < NJT; ++jt) {
        const bf16x8 bf = __builtin_bit_cast(bf16x8, FR[jt*64 + l]);
        f32x16 acc0 = __builtin_amdgcn_mfma_f32_32x32x16_bf16(a0, bf, ck, 0, 0, 0);
        f32x16 acc1 = __builtin_amdgcn_mfma_f32_32x32x16_bf16(a1, bf, ck, 0, 0, 0);
#pragma unroll
        for (int r = 0; r < 16; ++r) best0[r] = fmaxf(best0[r], acc0[r]);
#pragma unroll
        for (int r = 0; r < 16; ++r) best1[r] = fmaxf(best1[r], acc1[r]);
    }

    // ---- epilogue: max-reduce over the 32 cols (lanes within 32-group),
    //      then one atomicMax per output row from lanes 0 and 32 ----
    int* gk = gkey + (size_t)b * NN + (size_t)ib * QB;
    const int g = l >> 5;
#pragma unroll
    for (int ii = 0; ii < 2; ++ii) {
        const f32x16 bb = ii ? best1 : best0;
#pragma unroll
        for (int r = 0; r < 16; ++r) {
            float v = bb[r];
            v = fmaxf(v, __shfl_xor(v, 1, 64));
            v = fmaxf(v, __shfl_xor(v, 2, 64));
            v = fmaxf(v, __shfl_xor(v, 4, 64));
            v = fmaxf(v, __shfl_xor(v, 8, 64));
            v = fmaxf(v, __shfl_xor(v, 16, 64));
            if ((l & 31) == 0) {
                const int row = (r & 3) + 8 * (r >> 2) + 4 * g;
                atomicMax(&gk[(w*2 + ii)*32 + row], __float_as_int(v));
            }
        }
    }
}

// Kernel 2: single block, sum d2 = KEY_C - key over all B*N points -> mean.
__global__ __launch_bounds__(1024) void final_sum(
    const int* __restrict__ gkey,   // [B*N]
    float* __restrict__ out)
{
    const int t = threadIdx.x;  // 1024 threads = 16 waves
    const int4* g4 = (const int4*)gkey;
    float acc = 0.0f;
#pragma unroll
    for (int i = t; i < BN / 4; i += 1024) {
        int4 k = g4[i];
        acc += (KEY_C - __int_as_float(k.x)) + (KEY_C - __int_as_float(k.y))
             + (KEY_C - __int_as_float(k.z)) + (KEY_C - __int_as_float(k.w));
    }
    for (int off = 32; off > 0; off >>= 1) {
        acc += __shfl_down(acc, off, 64);
    }
    __shared__ float wsum[16];
    const int lane = t & 63;
    const int w    = t >> 6;
    if (lane == 0) wsum[w] = acc;
    __syncthreads();
    if (t == 0) {
        float tot = 0.0f;
#pragma unroll
        for (int i = 0; i < 16; ++i) tot += wsum[i];
        out[0] = tot * (1.0f / (float)BN);
    }
}

extern "C" void kernel_launch(void* const* d_in, const int* in_sizes, int n_in,
                              void* d_out, int out_size, void* d_ws, size_t ws_size,
                              hipStream_t stream) {
    // setup_inputs order: d_in[0] = v (targets y), d_in[1] = v_pred (queries x)
    const float* v      = (const float*)d_in[0];
    const float* v_pred = (const float*)d_in[1];
    float* out = (float*)d_out;

    int* gkey = (int*)d_ws;                  // [B*N] = 128 KB (poison loses atomicMax)

    dim3 grid1(NN / QB, SCH, BB);            // (32, 8, 4) = 1024 blocks
    chamfer_mfma<<<grid1, BLK, 0, stream>>>(v, v_pred, gkey);

    final_sum<<<1, 1024, 0, stream>>>(gkey, out);
}